// Round 6
// baseline (164.532 us; speedup 1.0000x reference)
//
#include <hip/hip_runtime.h>
#include <math.h>

// AutoregressiveFlowLayer MI355X — round 15.
// R14 post-mortem (REGRESSION, main 75.7us + gather ~11us): split-kernel xg
// round-trips through HBM (FETCH 65->117MB, WRITE 2->44.5MB) because per-XCD
// L2s don't share the freshly-written intermediate. Lesson: fuse, never pass
// hot intermediates across the XCD boundary. BUT R14 showed occupancy 75-79%
// (vs 42-47 in R12/R13) with (512,8) + 39.4KB LDS -> high residency is
// achievable; R12 was leaving it on the table.
// R15 = fused R12 2-barrier dataflow (single h1/h2 planes!) with LDS crushed
// to 23.5KB and __launch_bounds__(512,8):
//  - h1, h2 single planes (2-barrier schedule needs no double-buffer): 17.4KB
//  - xgh[2] fp16 (xgf dropped; fp16 epilogue x validated R13/R14): 5.1KB
//  - red_all[8] -> red2[2] (1KB) + per-interval out-store of tile t-2
//    (write B(t) / read A(t+2), barrier-separated)
//  - idx_s/v_s LDS arrays -> per-lane regs loaded straight from global
//  Total 23552B; grid 1024 = 4 blocks/CU exactly; thread-capped not LDS-capped.
// Kept: fp16 single-plane MFMA, weights=A register frags (proven <=64 regs at
// (512,8) in R14), dual-scratch weight staging (scratch aliases h1/h2), T14
// gather issue(t+2)-in-B / store(t+1)-in-A.

#define RR 32
#define DD 1024
#define HH 128
#define OO 64
#define TROWS 32
#define TILES_PER_BLOCK 8
#define BLOCKS_PER_R 32

#define SHP 136   // u16 stride, h planes [row][feat] (bank-balanced, 16B-aligned rows)
#define SXG 40    // u16 stride, xg plane [row][feat] (16B-aligned rows)
#define SSC 136   // u16 scratch stride (weight staging, [col][k])

typedef _Float16 f16x8_t __attribute__((ext_vector_type(8)));
typedef float f32x4_t __attribute__((ext_vector_type(4)));
typedef unsigned short u16;
typedef unsigned int u32;

__device__ __forceinline__ u16 f16b(float x) {
    _Float16 h = (_Float16)x;            // v_cvt_f16_f32, RNE
    union { _Float16 f; u16 u; } c; c.f = h; return c.u;
}
__device__ __forceinline__ f32x4_t mfma16h(f16x8_t a, f16x8_t b, f32x4_t c) {
    return __builtin_amdgcn_mfma_f32_16x16x32_f16(a, b, c, 0, 0, 0);
}

// stage [K x 32] weight slice (row-major [k][col], ld ldc, col offset c0) into
// fp16 [col][k] scratch, conflict-free 4x4 transpose. tid in [0,256).
__device__ __forceinline__ void stage_block16(const float* __restrict__ W,
                                              const int* __restrict__ M,
                                              int ldc, int c0, int K, u16* dst,
                                              int tid)
{
    const int kb = tid >> 3;
    const int cb = tid & 7;
    if (kb * 4 >= K) return;
    const int k0 = kb * 4;
    float e[4][4];
#pragma unroll
    for (int i = 0; i < 4; ++i) {
        const int o = ((k0 + i) * ldc + c0 + 4 * cb) >> 2;
        float4 w = ((const float4*)W)[o];
        int4   m = ((const int4*)M)[o];
        e[i][0] = m.x ? w.x : 0.f; e[i][1] = m.y ? w.y : 0.f;
        e[i][2] = m.z ? w.z : 0.f; e[i][3] = m.w ? w.w : 0.f;
    }
#pragma unroll
    for (int j = 0; j < 4; ++j) {
        ushort4 p;
        p.x = f16b(e[0][j]); p.y = f16b(e[1][j]);
        p.z = f16b(e[2][j]); p.w = f16b(e[3][j]);
        *(ushort4*)&dst[(4 * cb + j) * SSC + k0] = p;
    }
}

// ReLU + fp16 pack of 4 accumulator values, one 8B store.
__device__ __forceinline__ void relu_store16(u16* __restrict__ dst, int o, f32x4_t a)
{
    ushort4 s;
    s.x = f16b(fmaxf(a[0], 0.f));
    s.y = f16b(fmaxf(a[1], 0.f));
    s.z = f16b(fmaxf(a[2], 0.f));
    s.w = f16b(fmaxf(a[3], 0.f));
    *(ushort4*)&dst[o] = s;
}

__global__ __launch_bounds__(512, 8)
void made_flow_r15(const float* __restrict__ inputs,
                   const float* __restrict__ W1,
                   const float* __restrict__ W2,
                   const float* __restrict__ Wout,
                   const int* __restrict__ idx,
                   const int* __restrict__ valid,
                   const int* __restrict__ M1,
                   const int* __restrict__ M2,
                   const int* __restrict__ Mout,
                   float* __restrict__ out)
{
    __shared__ __align__(16) u16 h1s[TROWS * SHP];      // 8704 B (staging scratch A)
    __shared__ __align__(16) u16 h2s[TROWS * SHP];      // 8704 B (staging scratch B)
    __shared__ __align__(16) u16 xgh[2][TROWS * SXG];   // 5120 B
    __shared__ __align__(16) float red2[2][TROWS][4];   // 1024 B
    // total 23552 B

    u16* const scr  = h1s;
    u16* const scr2 = h2s;

    const int tid  = threadIdx.x;
    const int r    = blockIdx.x / BLOCKS_PER_R;
    const int rb   = blockIdx.x % BLOCKS_PER_R;
    const int lane = tid & 63;
    const int wave = tid >> 6;     // 0..7
    const int q    = lane >> 4;
    const int l16  = lane & 15;
    const int wm3  = wave & 3;     // P3: o-col group 16*wm3
    const int ni3  = wave >> 2;    // P3: batch-row half

    // per-lane metadata straight from global (no LDS arrays)
    const int grow = tid >> 4;     // 0..31 batch row (gather role)
    const int gg   = tid & 15;     // col pair (gather role)
    const int   ci0 = idx[r * RR + 2 * gg];
    const int   ci1 = idx[r * RR + 2 * gg + 1];
    const float cv0 = valid[r * RR + 2 * gg]     ? 1.f : 0.f;
    const float cv1 = valid[r * RR + 2 * gg + 1] ? 1.f : 0.f;
    const int j0  = 8 * wm3 + 2 * q;                    // epilogue cols
    const float vj0 = valid[r * RR + j0]     ? 1.f : 0.f;
    const float vj1 = valid[r * RR + j0 + 1] ? 1.f : 0.f;

    // ---- stage all weights -> per-wave fp16 register A-frags (W^T) via dual scratch ----
    f16x8_t a1;        // W1^T: wave cols 16w+l16, k=q*8..
    f16x8_t a2[4];     // W2^T: [ks], wave cols 16w+l16
    f16x8_t ao[4];     // Wout^T: cols 16*wm3+l16, [ks]
    {
        const float* W1r = W1 + r * RR * HH;   const int* M1r = M1 + r * RR * HH;
        const float* W2r = W2 + r * HH * HH;   const int* M2r = M2 + r * HH * HH;
        const float* Wor = Wout + r * HH * OO; const int* Mor = Mout + r * HH * OO;
        const int c = wave >> 1, h = wave & 1;
        for (int i = 0; i < 2; ++i) {
            __syncthreads();
            if (tid < 256) stage_block16(W2r, M2r, HH, 32 * (2 * i),     HH, scr,  tid);
            else           stage_block16(W2r, M2r, HH, 32 * (2 * i + 1), HH, scr2, tid - 256);
            __syncthreads();
            if (c == 2 * i) {
#pragma unroll
                for (int ks = 0; ks < 4; ++ks)
                    a2[ks] = *(const f16x8_t*)&scr[(16 * h + l16) * SSC + ks * 32 + q * 8];
            } else if (c == 2 * i + 1) {
#pragma unroll
                for (int ks = 0; ks < 4; ++ks)
                    a2[ks] = *(const f16x8_t*)&scr2[(16 * h + l16) * SSC + ks * 32 + q * 8];
            }
        }
        {
            __syncthreads();
            if (tid < 256) stage_block16(Wor, Mor, OO, 0,  HH, scr,  tid);
            else           stage_block16(Wor, Mor, OO, 32, HH, scr2, tid - 256);
            __syncthreads();
            const u16* s = (wm3 >> 1) ? scr2 : scr;
#pragma unroll
            for (int ks = 0; ks < 4; ++ks)
                ao[ks] = *(const f16x8_t*)&s[(16 * (wm3 & 1) + l16) * SSC + ks * 32 + q * 8];
        }
        for (int i = 0; i < 2; ++i) {
            __syncthreads();
            if (tid < 256) stage_block16(W1r, M1r, HH, 32 * (2 * i),     RR, scr,  tid);
            else           stage_block16(W1r, M1r, HH, 32 * (2 * i + 1), RR, scr2, tid - 256);
            __syncthreads();
            if (c == 2 * i)          a1 = *(const f16x8_t*)&scr [(16 * h + l16) * SSC + q * 8];
            else if (c == 2 * i + 1) a1 = *(const f16x8_t*)&scr2[(16 * h + l16) * SSC + q * 8];
        }
    }
    __syncthreads();   // scratch reads done before xg/h1 writes

    const f32x4_t zero4 = {0.f, 0.f, 0.f, 0.f};
    const int gbase = (rb * TILES_PER_BLOCK * TROWS + grow) * DD;

    // ---- prologue: gather(0) -> xgh[0]; issue gather(1) into regs ----
    float gx0, gx1;
    {
        float a0 = inputs[gbase + ci0] * cv0;
        float a1v = inputs[gbase + ci1] * cv1;
        *(u32*)&xgh[0][grow * SXG + 2 * gg] = (u32)f16b(a0) | ((u32)f16b(a1v) << 16);
        gx0 = inputs[gbase + TROWS * DD + ci0] * cv0;
        gx1 = inputs[gbase + TROWS * DD + ci1] * cv1;
    }
    __syncthreads();

    // ---- prologue: P1(0) -> h1s ----
    {
#pragma unroll
        for (int ni = 0; ni < 2; ++ni) {
            f16x8_t b = *(const f16x8_t*)&xgh[0][(16 * ni + l16) * SXG + q * 8];
            f32x4_t a = mfma16h(a1, b, zero4);
            relu_store16(h1s, (16 * ni + l16) * SHP + 16 * wave + 4 * q, a);
        }
    }

    for (int t = 0; t < TILES_PER_BLOCK; ++t) {
        __syncthreads();   // head barrier

        const bool dg = (t + 1 < TILES_PER_BLOCK);

        // ========== interval A: gather-store(t+1) + P2(t) + out-store(t-2) ========
        if (dg) {
            *(u32*)&xgh[(t + 1) & 1][grow * SXG + 2 * gg] =
                (u32)f16b(gx0) | ((u32)f16b(gx1) << 16);
        }
        {
            // P2(t): h2^T = W2^T @ h1^T (wave owns 16 of M=128 cols, both ni, K=128)
            f32x4_t acc[2] = {zero4, zero4};
#pragma unroll
            for (int ks = 0; ks < 4; ++ks) {
#pragma unroll
                for (int ni = 0; ni < 2; ++ni) {
                    f16x8_t b = *(const f16x8_t*)&h1s[(16 * ni + l16) * SHP + ks * 32 + q * 8];
                    acc[ni] = mfma16h(a2[ks], b, acc[ni]);
                }
            }
#pragma unroll
            for (int ni = 0; ni < 2; ++ni)
                relu_store16(h2s, (16 * ni + l16) * SHP + 16 * wave + 4 * q, acc[ni]);
        }
        if (t >= 2 && tid < TROWS) {
            float4 rv = *(const float4*)&red2[t & 1][tid][0];
            out[((rb * TILES_PER_BLOCK + (t - 2)) * TROWS + tid) * RR + r] =
                rv.x + rv.y + rv.z + rv.w;
        }
        __syncthreads();   // mid barrier

        // ========== interval B: gather-issue(t+2) + P3(t) + P1(t+1) + epilogue(t) ==
        if (t + 2 < TILES_PER_BLOCK) {
            const int base = gbase + (t + 2) * (TROWS * DD);
            gx0 = inputs[base + ci0] * cv0;
            gx1 = inputs[base + ci1] * cv1;
        }

        // P3(t): out^T = Wout^T @ h2^T; wave (wm3,ni3): o=16*wm3+4q+i, row=16*ni3+l16
        f32x4_t acc3 = zero4;
#pragma unroll
        for (int ks = 0; ks < 4; ++ks) {
            f16x8_t b = *(const f16x8_t*)&h2s[(16 * ni3 + l16) * SHP + ks * 32 + q * 8];
            acc3 = mfma16h(ao[ks], b, acc3);
        }

        if (dg) {   // P1(t+1): h1^T = W1^T @ xg^T
#pragma unroll
            for (int ni = 0; ni < 2; ++ni) {
                f16x8_t b = *(const f16x8_t*)&xgh[(t + 1) & 1][(16 * ni + l16) * SXG + q * 8];
                f32x4_t a = mfma16h(a1, b, zero4);
                relu_store16(h1s, (16 * ni + l16) * SHP + 16 * wave + 4 * q, a);
            }
        }

        {   // epilogue(t): acc3[i]: i even=shift(j), i odd=log_s(j), j=8*wm3+2q+(i>>1)
            const int row = 16 * ni3 + l16;
            u32 xw = *(const u32*)&xgh[t & 1][row * SXG + j0];
            union { u32 u; _Float16 h[2]; } xc; xc.u = xw;
            const float xv0 = (float)xc.h[0], xv1 = (float)xc.h[1];
            const float u0 = (xv0 - acc3[0]) * __expf(-acc3[1]);
            const float u1 = (xv1 - acc3[2]) * __expf(-acc3[3]);
            float p = (-0.5f * u0 * u0 - 0.91893853320467266954f - acc3[1]) * vj0
                    + (-0.5f * u1 * u1 - 0.91893853320467266954f - acc3[3]) * vj1;
            p += __shfl_xor(p, 16, 64);
            p += __shfl_xor(p, 32, 64);
            if (q == 0) red2[t & 1][row][wm3] = p;
        }
    }

    // ---- tail: store tiles T-2 and T-1 ----
    __syncthreads();
    if (tid < 2 * TROWS) {
        const int tt  = TILES_PER_BLOCK - 2 + (tid >> 5);   // T-2, T-1
        const int row = tid & 31;
        float4 rv = *(const float4*)&red2[tt & 1][row][0];
        out[((rb * TILES_PER_BLOCK + tt) * TROWS + row) * RR + r] =
            rv.x + rv.y + rv.z + rv.w;
    }
}

extern "C" void kernel_launch(void* const* d_in, const int* in_sizes, int n_in,
                              void* d_out, int out_size, void* d_ws, size_t ws_size,
                              hipStream_t stream)
{
    const float* inputs = (const float*)d_in[0];
    const float* W1     = (const float*)d_in[1];
    const float* W2     = (const float*)d_in[2];
    const float* Wout   = (const float*)d_in[3];
    const int*   idx    = (const int*)d_in[4];
    const int*   valid  = (const int*)d_in[5];
    const int*   M1     = (const int*)d_in[6];
    const int*   M2     = (const int*)d_in[7];
    const int*   Mout   = (const int*)d_in[8];
    float*       out    = (float*)d_out;

    hipLaunchKernelGGL(made_flow_r15, dim3(RR * BLOCKS_PER_R), dim3(512), 0, stream,
                       inputs, W1, W2, Wout, idx, valid, M1, M2, Mout, out);
}

// Round 7
// 120.405 us; speedup vs baseline: 1.3665x; 1.3665x over previous
//
#include <hip/hip_runtime.h>
#include <math.h>

// AutoregressiveFlowLayer MI355X — round 16.
// R15 post-mortem (REGRESSION 92us): __launch_bounds__(512,8) forced a <=64-reg
// cap; real demand ~75-85 -> compiler spilled (VGPR_Count 40->32, WRITE_SIZE
// 70MB vs ~1MB real output, FETCH +65MB = scratch round-trips). R14's "75%
// occupancy" carried the same spill signature — retracted as evidence.
// Register arithmetic: weight-resident design needs ~75-85 regs -> hard cap
// 6 waves/SIMD = 3 blocks(512)/CU. R12/R13's 42-47% occupancy = grid 1024
// (4 blocks/CU of work) on 3-resident CUs -> phase(3-parallel)+phase(1-alone).
// R16 = R13 dataflow UNCHANGED, grid matched to residency: 768 blocks =
// exactly 3/CU, all resident; BLOCKS_PER_R 24, blocks carry 11 or 10 tiles
// (16*11 + 8*10 = 256). LDS 51.2KB (red_all[11]); 3x51.2 = 153.6 <= 160 ✓.
// launch_bounds stays (512,6) — the proven no-spill point.
// Kept: fp16 single-plane MFMA, weights=A register frags, single barrier/tile,
// xgh 4-deep, dual-scratch weight staging, red_all + single tail store.

#define RR 32
#define DD 1024
#define HH 128
#define OO 64
#define TROWS 32
#define BLOCKS_PER_R 24
#define MAXT 11

#define SHP 136   // u16 stride, h planes [row][feat] (bank-balanced)
#define SXG 40    // u16 stride, xg plane [row][feat]
#define SSC 136   // u16 scratch stride (weight staging, [col][k])

typedef _Float16 f16x8_t __attribute__((ext_vector_type(8)));
typedef float f32x4_t __attribute__((ext_vector_type(4)));
typedef unsigned short u16;
typedef unsigned int u32;

__device__ __forceinline__ u16 f16b(float x) {
    _Float16 h = (_Float16)x;            // v_cvt_f16_f32, RNE
    union { _Float16 f; u16 u; } c; c.f = h; return c.u;
}
__device__ __forceinline__ f32x4_t mfma16h(f16x8_t a, f16x8_t b, f32x4_t c) {
    return __builtin_amdgcn_mfma_f32_16x16x32_f16(a, b, c, 0, 0, 0);
}

// stage [K x 32] weight slice (row-major [k][col], ld ldc, col offset c0) into
// fp16 [col][k] scratch, conflict-free 4x4 transpose. tid in [0,256).
__device__ __forceinline__ void stage_block16(const float* __restrict__ W,
                                              const int* __restrict__ M,
                                              int ldc, int c0, int K, u16* dst,
                                              int tid)
{
    const int kb = tid >> 3;
    const int cb = tid & 7;
    if (kb * 4 >= K) return;
    const int k0 = kb * 4;
    float e[4][4];
#pragma unroll
    for (int i = 0; i < 4; ++i) {
        const int o = ((k0 + i) * ldc + c0 + 4 * cb) >> 2;
        float4 w = ((const float4*)W)[o];
        int4   m = ((const int4*)M)[o];
        e[i][0] = m.x ? w.x : 0.f; e[i][1] = m.y ? w.y : 0.f;
        e[i][2] = m.z ? w.z : 0.f; e[i][3] = m.w ? w.w : 0.f;
    }
#pragma unroll
    for (int j = 0; j < 4; ++j) {
        ushort4 p;
        p.x = f16b(e[0][j]); p.y = f16b(e[1][j]);
        p.z = f16b(e[2][j]); p.w = f16b(e[3][j]);
        *(ushort4*)&dst[(4 * cb + j) * SSC + k0] = p;
    }
}

// ReLU + fp16 pack of 4 accumulator values, one 8B store.
__device__ __forceinline__ void relu_store16(u16* __restrict__ dst, int o, f32x4_t a)
{
    ushort4 s;
    s.x = f16b(fmaxf(a[0], 0.f));
    s.y = f16b(fmaxf(a[1], 0.f));
    s.z = f16b(fmaxf(a[2], 0.f));
    s.w = f16b(fmaxf(a[3], 0.f));
    *(ushort4*)&dst[o] = s;
}

__global__ __launch_bounds__(512, 6)
void made_flow_r16(const float* __restrict__ inputs,
                   const float* __restrict__ W1,
                   const float* __restrict__ W2,
                   const float* __restrict__ Wout,
                   const int* __restrict__ idx,
                   const int* __restrict__ valid,
                   const int* __restrict__ M1,
                   const int* __restrict__ M2,
                   const int* __restrict__ Mout,
                   float* __restrict__ out)
{
    __shared__ __align__(16) u16 h1s[2][TROWS * SHP];   // 17408 B (also staging scratch)
    __shared__ __align__(16) u16 h2s[2][TROWS * SHP];   // 17408 B
    __shared__ __align__(16) u16 xgh[4][TROWS * SXG];   // 10240 B
    __shared__ __align__(16) float red_all[MAXT][TROWS][4];  // 5632 B
    __shared__ int   idx_s[RR];
    __shared__ float v_s[RR];
    // total ~51.2 KB -> 3 blocks/CU

    u16* const scr  = h1s[0];
    u16* const scr2 = h1s[1];

    const int tid  = threadIdx.x;
    const int r    = blockIdx.x / BLOCKS_PER_R;
    const int rb   = blockIdx.x % BLOCKS_PER_R;
    // tile range: first 16 blocks take 11 tiles, last 8 take 10 (total 256)
    const int ts   = (rb < 16) ? 11 * rb : 176 + 10 * (rb - 16);
    const int nt   = (rb < 16) ? 11 : 10;

    const int lane = tid & 63;
    const int wave = tid >> 6;     // 0..7
    const int q    = lane >> 4;
    const int l16  = lane & 15;
    const int wm3  = wave & 3;     // P3: o-col group 16*wm3
    const int ni3  = wave >> 2;    // P3: batch-row half

    if (tid < RR) {
        idx_s[tid] = idx[r * RR + tid];
        v_s[tid]   = valid[r * RR + tid] ? 1.f : 0.f;
    }

    // ---- stage all weights -> per-wave fp16 register A-frags (W^T) via dual scratch ----
    f16x8_t a1;        // W1^T: wave cols 16w+l16, k=q*8..
    f16x8_t a2[4];     // W2^T: [ks], wave cols 16w+l16
    f16x8_t ao[4];     // Wout^T: cols 16*wm3+l16, [ks]
    {
        const float* W1r = W1 + r * RR * HH;   const int* M1r = M1 + r * RR * HH;
        const float* W2r = W2 + r * HH * HH;   const int* M2r = M2 + r * HH * HH;
        const float* Wor = Wout + r * HH * OO; const int* Mor = Mout + r * HH * OO;
        const int c = wave >> 1, h = wave & 1;
        for (int i = 0; i < 2; ++i) {
            __syncthreads();
            if (tid < 256) stage_block16(W2r, M2r, HH, 32 * (2 * i),     HH, scr,  tid);
            else           stage_block16(W2r, M2r, HH, 32 * (2 * i + 1), HH, scr2, tid - 256);
            __syncthreads();
            if (c == 2 * i) {
#pragma unroll
                for (int ks = 0; ks < 4; ++ks)
                    a2[ks] = *(const f16x8_t*)&scr[(16 * h + l16) * SSC + ks * 32 + q * 8];
            } else if (c == 2 * i + 1) {
#pragma unroll
                for (int ks = 0; ks < 4; ++ks)
                    a2[ks] = *(const f16x8_t*)&scr2[(16 * h + l16) * SSC + ks * 32 + q * 8];
            }
        }
        {
            __syncthreads();
            if (tid < 256) stage_block16(Wor, Mor, OO, 0,  HH, scr,  tid);
            else           stage_block16(Wor, Mor, OO, 32, HH, scr2, tid - 256);
            __syncthreads();
            const u16* s = (wm3 >> 1) ? scr2 : scr;
#pragma unroll
            for (int ks = 0; ks < 4; ++ks)
                ao[ks] = *(const f16x8_t*)&s[(16 * (wm3 & 1) + l16) * SSC + ks * 32 + q * 8];
        }
        for (int i = 0; i < 2; ++i) {
            __syncthreads();
            if (tid < 256) stage_block16(W1r, M1r, HH, 32 * (2 * i),     RR, scr,  tid);
            else           stage_block16(W1r, M1r, HH, 32 * (2 * i + 1), RR, scr2, tid - 256);
            __syncthreads();
            if (c == 2 * i)          a1 = *(const f16x8_t*)&scr [(16 * h + l16) * SSC + q * 8];
            else if (c == 2 * i + 1) a1 = *(const f16x8_t*)&scr2[(16 * h + l16) * SSC + q * 8];
        }
    }
    __syncthreads();   // scratch reads done before xg/h1 writes

    const f32x4_t zero4 = {0.f, 0.f, 0.f, 0.f};
    const int grow = tid >> 4;     // 0..31 batch row
    const int gg   = tid & 15;     // col pair: 2*gg, 2*gg+1

    const int   ci0 = idx_s[2 * gg], ci1 = idx_s[2 * gg + 1];
    const float cv0 = v_s[2 * gg],   cv1 = v_s[2 * gg + 1];
    const int   gbase = (ts * TROWS + grow) * DD;

    // ---- prologue: gather(0) and gather(1) ----
    {
        float a0 = inputs[gbase + ci0] * cv0;
        float a1v = inputs[gbase + ci1] * cv1;
        float b0 = inputs[gbase + TROWS * DD + ci0] * cv0;
        float b1 = inputs[gbase + TROWS * DD + ci1] * cv1;
        *(u32*)&xgh[0][grow * SXG + 2 * gg] = (u32)f16b(a0) | ((u32)f16b(a1v) << 16);
        *(u32*)&xgh[1][grow * SXG + 2 * gg] = (u32)f16b(b0) | ((u32)f16b(b1) << 16);
    }
    __syncthreads();

    // ---- prologue: P1(0) -> h1s[0] ----
    {
#pragma unroll
        for (int ni = 0; ni < 2; ++ni) {
            f16x8_t b = *(const f16x8_t*)&xgh[0][(16 * ni + l16) * SXG + q * 8];
            f32x4_t a = mfma16h(a1, b, zero4);
            relu_store16(h1s[0], (16 * ni + l16) * SHP + 16 * wave + 4 * q, a);
        }
    }

    // ---- main loop: ONE barrier per tile (runtime trip count nt) ----
    for (int t = 0; t <= nt; ++t) {
        __syncthreads();

        const bool doP2  = (t < nt);
        const bool doP3  = (t >= 1);
        const bool doP1n = (t + 1 < nt);
        const bool doG   = (t + 2 < nt);

        // gather-issue(t+2): longest latency first
        float gx0, gx1;
        if (doG) {
            const int base = gbase + (t + 2) * (TROWS * DD);
            gx0 = inputs[base + ci0] * cv0;
            gx1 = inputs[base + ci1] * cv1;
        }

        // P3(t-1): out^T = Wout^T @ h2^T; wave (wm3,ni3): o=16*wm3+4q+i, row=16*ni3+l16
        f32x4_t acc3 = zero4;
        if (doP3) {
            const u16* h2b = h2s[(t - 1) & 1];
#pragma unroll
            for (int ks = 0; ks < 4; ++ks) {
                f16x8_t b = *(const f16x8_t*)&h2b[(16 * ni3 + l16) * SHP + ks * 32 + q * 8];
                acc3 = mfma16h(ao[ks], b, acc3);
            }
        }

        // P2(t): h2^T = W2^T @ h1^T (wave owns 16 of M=128 cols, both ni, K=128)
        if (doP2) {
            const u16* h1b = h1s[t & 1];
            u16*       h2b = h2s[t & 1];
            f32x4_t acc[2] = {zero4, zero4};
#pragma unroll
            for (int ks = 0; ks < 4; ++ks) {
#pragma unroll
                for (int ni = 0; ni < 2; ++ni) {
                    f16x8_t b = *(const f16x8_t*)&h1b[(16 * ni + l16) * SHP + ks * 32 + q * 8];
                    acc[ni] = mfma16h(a2[ks], b, acc[ni]);
                }
            }
#pragma unroll
            for (int ni = 0; ni < 2; ++ni)
                relu_store16(h2b, (16 * ni + l16) * SHP + 16 * wave + 4 * q, acc[ni]);
        }

        // P1(t+1): h1^T = W1^T @ xg^T
        if (doP1n) {
            const u16* xb  = xgh[(t + 1) & 3];
            u16*       h1b = h1s[(t + 1) & 1];
#pragma unroll
            for (int ni = 0; ni < 2; ++ni) {
                f16x8_t b = *(const f16x8_t*)&xb[(16 * ni + l16) * SXG + q * 8];
                f32x4_t a = mfma16h(a1, b, zero4);
                relu_store16(h1b, (16 * ni + l16) * SHP + 16 * wave + 4 * q, a);
            }
        }

        // epilogue(t-1): acc3[i]: i even=shift(j), i odd=log_s(j), j=8*wm3+2q+(i>>1)
        if (doP3) {
            const int j0 = 8 * wm3 + 2 * q;
            const float vj0 = v_s[j0], vj1 = v_s[j0 + 1];
            const int row = 16 * ni3 + l16;
            u32 xw = *(const u32*)&xgh[(t - 1) & 3][row * SXG + j0];
            union { u32 u; _Float16 h[2]; } xc; xc.u = xw;
            const float xv0 = (float)xc.h[0], xv1 = (float)xc.h[1];
            const float u0 = (xv0 - acc3[0]) * __expf(-acc3[1]);
            const float u1 = (xv1 - acc3[2]) * __expf(-acc3[3]);
            float p = (-0.5f * u0 * u0 - 0.91893853320467266954f - acc3[1]) * vj0
                    + (-0.5f * u1 * u1 - 0.91893853320467266954f - acc3[3]) * vj1;
            p += __shfl_xor(p, 16, 64);
            p += __shfl_xor(p, 32, 64);
            if (q == 0) red_all[t - 1][row][wm3] = p;
        }

        // gather-store(t+2)
        if (doG) {
            *(u32*)&xgh[(t + 2) & 3][grow * SXG + 2 * gg] =
                (u32)f16b(gx0) | ((u32)f16b(gx1) << 16);
        }
    }

    // ---- tail: reduce red_all across wm3, single batched global store ----
    __syncthreads();
    if (tid < nt * TROWS) {
        const int tt  = tid >> 5;      // 0..nt-1
        const int row = tid & 31;
        float4 rv = *(const float4*)&red_all[tt][row][0];
        out[((ts + tt) * TROWS + row) * RR + r] =
            rv.x + rv.y + rv.z + rv.w;
    }
}

extern "C" void kernel_launch(void* const* d_in, const int* in_sizes, int n_in,
                              void* d_out, int out_size, void* d_ws, size_t ws_size,
                              hipStream_t stream)
{
    const float* inputs = (const float*)d_in[0];
    const float* W1     = (const float*)d_in[1];
    const float* W2     = (const float*)d_in[2];
    const float* Wout   = (const float*)d_in[3];
    const int*   idx    = (const int*)d_in[4];
    const int*   valid  = (const int*)d_in[5];
    const int*   M1     = (const int*)d_in[6];
    const int*   M2     = (const int*)d_in[7];
    const int*   Mout   = (const int*)d_in[8];
    float*       out    = (float*)d_out;

    hipLaunchKernelGGL(made_flow_r16, dim3(RR * BLOCKS_PER_R), dim3(512), 0, stream,
                       inputs, W1, W2, Wout, idx, valid, M1, M2, Mout, out);
}